// Round 24
// baseline (257.619 us; speedup 1.0000x reference)
//
#include <hip/hip_runtime.h>
#include <hip/hip_bf16.h>
#include <cstdint>

#define DI __device__ __forceinline__

using bf16x8 = __attribute__((ext_vector_type(8))) short;
using f32x4  = __attribute__((ext_vector_type(4))) float;

constexpr int IN_DIM = 384;
constexpr int HID    = 512;
constexpr int KTOT   = IN_DIM * 20;          // 7680: k = i*20 + t
constexpr int BM = 64, BN = 512, BK = 160;   // 8 input dims per K-step; BN = full HID
constexpr int NSTEP = KTOT / BK;             // 48
// R23 champion (243 us) + FUSED FINAL: since BN=HID, each block holds complete h-rows;
// after the K-loop the LDS A-buffers are dead -> write tanh(acc) as bf16 h-tile [64][512]
// (stride 1024B, proven XOR swizzle addr^(row&7)<<4), barrier, then each wave MFMAs a
// 16-row x 32-outcol strip of out = h @ lw^T + lb (B-frags straight from lw, fp32->bf16
// in-register -- numerically identical to the old kfinal). Kills the kfinal dispatch and
// the 64MB h HBM round-trip.
constexpr int A_STRIDE_B = 320;
constexpr int A_BYTES    = BM * A_STRIDE_B;        // 20480
constexpr int LDS_BYTES  = 65536;                  // loop uses 40960; epilogue h-tile 64KB
                                                   // 2 x 64KB = 128KB <= 160KB -> 2 blocks/CU

DI unsigned short f2bf(float f) {
  union { float f; uint32_t u; } v; v.f = f;
  uint32_t r = (v.u + 0x7FFFu + ((v.u >> 16) & 1u)) >> 16;
  return (unsigned short)r;
}
DI float fast_tanh(float x) {
  float e = __expf(2.0f * x);
  return 1.0f - 2.0f / (e + 1.0f);
}

// ---------------- kpack: W -> bf16 fragment-linear Wf (16x16x32 layout, R18-verbatim) ----
__global__ __launch_bounds__(256) void kpack(const float* __restrict__ bw,
                                             const float* __restrict__ sw,
                                             unsigned short* __restrict__ Wf) {
  int idx = blockIdx.x * 256 + threadIdx.x;   // o*384 + i
  int o = idx / IN_DIM;
  int i = idx - o * IN_DIM;
  const float* sp = sw + (size_t)idx * 19;
  const uint32_t gq  = (uint32_t)(o >> 4);
  const uint32_t l16o = (uint32_t)(o & 15);
#pragma unroll
  for (int c = 0; c < 20; ++c) {
    int k = i * 20 + c;
    uint32_t q  = (uint32_t)k >> 5;
    uint32_t kr = (uint32_t)k & 31u;
    uint32_t lane = l16o + ((kr >> 3) << 4);
    uint32_t off = (q * 32u + gq) * 512u + lane * 8u + (kr & 7u);
    float v = (c == 0) ? bw[idx] : sp[c - 1];
    Wf[off] = f2bf(v);
  }
}

// ---------------- fused KAN GEMM + final: out = tanh(A(x)@W^T) @ lw^T + lb ----------------
__global__ __launch_bounds__(512, 4) void kgemm1(const float* __restrict__ z,
                                                 const float* __restrict__ ms,
                                                 const float* __restrict__ md,
                                                 const unsigned short* __restrict__ Wf,
                                                 const float* __restrict__ lw,
                                                 const float* __restrict__ lb,
                                                 float* __restrict__ out) {
  extern __shared__ char ldsbuf[];            // loop: [A0 @0][A1 @20480]; epilogue: h-tile 64KB

  const int tid  = threadIdx.x;
  const int lane = tid & 63;
  const int wc   = tid >> 6;                  // 0..7 : N strip (64 cols); all waves share rows
  const int l16  = lane & 15;
  const int lhi  = lane >> 4;

  // XCD-aware bijective swizzle: grid 512 = 8 XCD * 64 (pure M split; every block scans W)
  int wg = blockIdx.x;
  int id = (wg & 7) * 64 + (wg >> 3);
  const int row0 = id * BM;

  // B global fragment base: g = wc*4 + ni in [0,32); q = s*5 + ks (frag stride 16384 elems)
  const unsigned short* bpt = Wf + (size_t)(wc * 4) * 512 + (size_t)lane * 8;

  // A-gen: exactly ONE task per thread (64 rows x 8 isl = 512)
  const int isl = tid & 7;
  const int arow = tid >> 3;                  // 0..63
  const uint32_t fw = ((uint32_t)arow & 7u) << 4;
  const uint32_t abase = (uint32_t)arow * A_STRIDE_B + (uint32_t)isl * 40u;

  // A fragment read base (XOR applied to full address; R18-verbatim)
  const uint32_t fA = (uint32_t)(l16 & 7) << 4;      // row&7 = l16&7
  const uint32_t rA = (uint32_t)l16 * A_STRIDE_B + (uint32_t)lhi * 16u;

  f32x4 acc[4][4] = {};

  // ---- prologue: stage A(0) into parity 0; prefetch x(1)
  float xv0;
  {
    float x = z[(size_t)(row0 + arow) * 128 + isl];   // s=0 -> i=isl<128 -> z
    float xt = fast_tanh(x);
    float tt = (xt + 1.0f) * 8.0f;
    int   m  = (int)tt; m = m > 16 ? 16 : m;
    float u  = tt - (float)m;
    float omu = 1.0f - u;
    float u2 = u * u, u3 = u2 * u;
    float w0 = omu * omu * omu * (1.0f / 6.0f);
    float w1 = (3.0f * u3 - 6.0f * u2 + 4.0f) * (1.0f / 6.0f);
    float w2 = (-3.0f * u3 + 3.0f * u2 + 3.0f * u + 1.0f) * (1.0f / 6.0f);
    float w3 = u3 * (1.0f / 6.0f);
    float sil = xt / (1.0f + __expf(-xt));
#pragma unroll
    for (int zz = 0; zz < 5; ++zz)
      *(uint64_t*)(ldsbuf + ((abase + zz * 8) ^ fw)) = 0ull;
    *(short*)(ldsbuf + (abase ^ fw)) = (short)f2bf(sil);
    *(short*)(ldsbuf + ((abase + 2u * (m + 1)) ^ fw)) = (short)f2bf(w0);
    *(short*)(ldsbuf + ((abase + 2u * (m + 2)) ^ fw)) = (short)f2bf(w1);
    *(short*)(ldsbuf + ((abase + 2u * (m + 3)) ^ fw)) = (short)f2bf(w2);
    if (m < 16)
      *(short*)(ldsbuf + ((abase + 2u * (m + 4)) ^ fw)) = (short)f2bf(w3);
    xv0 = z[(size_t)(row0 + arow) * 128 + 8 + isl];   // x(1)
  }
  __syncthreads();

  for (int s = 0; s < NSTEP; ++s) {
    const uint32_t pc = (uint32_t)(s & 1);
    const uint32_t pn = pc ^ 1u;
    char* An = ldsbuf + pn * (uint32_t)A_BYTES;
    const char* Ac = ldsbuf + pc * (uint32_t)A_BYTES;

    // ---- stage A(s+1) into An using xv0 = x(s+1) -- UNCONDITIONAL (branchless; step-48
    // tile is unread, reads memory-safe)
    {
      float xt = fast_tanh(xv0);
      float tt = (xt + 1.0f) * 8.0f;
      int   m  = (int)tt; m = m > 16 ? 16 : m;
      float u  = tt - (float)m;
      float omu = 1.0f - u;
      float u2 = u * u, u3 = u2 * u;
      float w0 = omu * omu * omu * (1.0f / 6.0f);
      float w1 = (3.0f * u3 - 6.0f * u2 + 4.0f) * (1.0f / 6.0f);
      float w2 = (-3.0f * u3 + 3.0f * u2 + 3.0f * u + 1.0f) * (1.0f / 6.0f);
      float w3 = u3 * (1.0f / 6.0f);
      float sil = xt / (1.0f + __expf(-xt));
#pragma unroll
      for (int zz = 0; zz < 5; ++zz)
        *(uint64_t*)(An + ((abase + zz * 8) ^ fw)) = 0ull;
      *(short*)(An + (abase ^ fw)) = (short)f2bf(sil);
      *(short*)(An + ((abase + 2u * (m + 1)) ^ fw)) = (short)f2bf(w0);
      *(short*)(An + ((abase + 2u * (m + 2)) ^ fw)) = (short)f2bf(w1);
      *(short*)(An + ((abase + 2u * (m + 3)) ^ fw)) = (short)f2bf(w2);
      if (m < 16)
        *(short*)(An + ((abase + 2u * (m + 4)) ^ fw)) = (short)f2bf(w3);
    }
    // ---- prefetch x(s+2), branchless: index wraps mod IN_DIM (wrapped value unused)
    float xn0;
    {
      int i = (s + 2) * 8 + isl;
      i = (i >= IN_DIM) ? (i - IN_DIM) : i;
      const float* src = (i < 128) ? z : (i < 256 ? ms : md);
      xn0 = src[(size_t)(row0 + arow) * 128 + (i & 127)];
    }

    // ---- compute(s): A frags from LDS (parity pc), B frags as coalesced 1KB global loads
    const size_t qoff = (size_t)s * 5u * 16384u;   // q = s*5 + ks
#pragma unroll
    for (int ks = 0; ks < 5; ++ks) {
      bf16x8 af[4], bfr[4];
#pragma unroll
      for (int ni = 0; ni < 4; ++ni)
        bfr[ni] = *(const bf16x8*)(bpt + qoff + (size_t)ks * 16384u + (size_t)ni * 512u);
#pragma unroll
      for (int mi = 0; mi < 4; ++mi)
        af[mi] = *(const bf16x8*)(Ac + ((rA + (uint32_t)(mi * 16) * A_STRIDE_B + ks * 64u) ^ fA));
#pragma unroll
      for (int mi = 0; mi < 4; ++mi)
#pragma unroll
        for (int ni = 0; ni < 4; ++ni)
          acc[mi][ni] = __builtin_amdgcn_mfma_f32_16x16x32_bf16(af[mi], bfr[ni], acc[mi][ni], 0, 0, 0);
    }

    __syncthreads();   // one barrier: A(s+1) writes visible; Ac safe to overwrite next step
    xv0 = xn0;
  }

  // ==== fused final: out = tanh(h) @ lw^T + lb, entirely in-block ====
  // 1. write tanh(acc) -> bf16 h-tile [64][512] in LDS, row stride 1024B, XOR swizzle
  //    addr^(row&7)<<4 (A-buffers are dead after the last barrier)
#pragma unroll
  for (int mi = 0; mi < 4; ++mi)
#pragma unroll
    for (int ni = 0; ni < 4; ++ni)
#pragma unroll
      for (int rg = 0; rg < 4; ++rg) {
        int hrow = mi * 16 + lhi * 4 + rg;
        int hcol = wc * 64 + ni * 16 + l16;
        uint32_t ha = (uint32_t)hrow * 1024u + (uint32_t)hcol * 2u;
        *(short*)(ldsbuf + (ha ^ (((uint32_t)hrow & 7u) << 4))) =
            (short)f2bf(fast_tanh(acc[mi][ni][rg]));
      }
  __syncthreads();

  // 2. each wave: rows strip (wc>>1)*16, ocols (wc&1)*32; K=512 over 16 ks; no reduction
  {
    const int rs  = (wc >> 1) * 16;
    const int oc0 = (wc & 1) * 32;
    const uint32_t rh = (uint32_t)(rs + l16) * 1024u + (uint32_t)lhi * 16u;
    const uint32_t fH = (uint32_t)(l16 & 7) << 4;   // (rs+l16)&7 = l16&7 (rs mult of 16)
    f32x4 acc2[2] = {};
#pragma unroll
    for (int ks = 0; ks < 16; ++ks) {
      bf16x8 ah = *(const bf16x8*)(ldsbuf + ((rh + (uint32_t)ks * 64u) ^ fH));
#pragma unroll
      for (int ni = 0; ni < 2; ++ni) {
        const float* lwp = lw + (size_t)(oc0 + ni * 16 + l16) * 512 + ks * 32 + lhi * 8;
        float4 f0 = *(const float4*)lwp;
        float4 f1 = *(const float4*)(lwp + 4);
        union { unsigned short sh[8]; bf16x8 v; } ub;
        ub.sh[0] = f2bf(f0.x); ub.sh[1] = f2bf(f0.y); ub.sh[2] = f2bf(f0.z); ub.sh[3] = f2bf(f0.w);
        ub.sh[4] = f2bf(f1.x); ub.sh[5] = f2bf(f1.y); ub.sh[6] = f2bf(f1.z); ub.sh[7] = f2bf(f1.w);
        acc2[ni] = __builtin_amdgcn_mfma_f32_16x16x32_bf16(ah, ub.v, acc2[ni], 0, 0, 0);
      }
    }
#pragma unroll
    for (int ni = 0; ni < 2; ++ni) {
      int ocol = oc0 + ni * 16 + l16;
      float bias = lb[ocol];
#pragma unroll
      for (int rg = 0; rg < 4; ++rg) {
        int grow = row0 + rs + lhi * 4 + rg;
        out[(size_t)grow * 64 + ocol] = acc2[ni][rg] + bias;
      }
    }
  }
}

extern "C" void kernel_launch(void* const* d_in, const int* in_sizes, int n_in,
                              void* d_out, int out_size, void* d_ws, size_t ws_size,
                              hipStream_t stream) {
  const float* z  = (const float*)d_in[0];
  const float* ms = (const float*)d_in[1];
  const float* md = (const float*)d_in[2];
  const float* bw = (const float*)d_in[3];
  const float* sw = (const float*)d_in[4];
  const float* lw = (const float*)d_in[5];
  const float* lb = (const float*)d_in[6];
  float* out = (float*)d_out;

  unsigned short* Wf = (unsigned short*)d_ws;   // 7.5 MiB fragment-linear W

  (void)hipFuncSetAttribute((const void*)kgemm1,
                            hipFuncAttributeMaxDynamicSharedMemorySize, LDS_BYTES);

  kpack<<<(HID * IN_DIM) / 256, 256, 0, stream>>>(bw, sw, Wf);
  kgemm1<<<512, 512, LDS_BYTES, stream>>>(z, ms, md, Wf, lw, lb, out);
}

// Round 25
// 242.962 us; speedup vs baseline: 1.0603x; 1.0603x over previous
//
#include <hip/hip_runtime.h>
#include <hip/hip_bf16.h>
#include <cstdint>

#define DI __device__ __forceinline__

using bf16x8 = __attribute__((ext_vector_type(8))) short;
using f32x4  = __attribute__((ext_vector_type(4))) float;

constexpr int IN_DIM = 384;
constexpr int HID    = 512;
constexpr int KTOT   = IN_DIM * 20;          // 7680: k = i*20 + t
constexpr int BM = 64, BN = 512, BK = 160;   // 8 input dims per K-step; BN = full HID
constexpr int NSTEP = KTOT / BK;             // 48
// R24 fused-final + fragment-linear lwf: R24's epilogue was throttled by uncoalesced fp32
// lw reads (16 cache lines per float4) + in-loop convert VALU. kpackL pre-packs lw into
// the SAME 16x16x32 B-fragment layout as Wf -> epilogue B-frags are single coalesced 1KB
// bf16 loads, zero conversion VALU. Main loop R23/R24-verbatim.
constexpr int A_STRIDE_B = 320;
constexpr int A_BYTES    = BM * A_STRIDE_B;        // 20480
constexpr int LDS_BYTES  = 65536;                  // loop 40960; epilogue h-tile 64KB
                                                   // 2 x 64KB = 128KB -> 2 blocks/CU

DI unsigned short f2bf(float f) {
  union { float f; uint32_t u; } v; v.f = f;
  uint32_t r = (v.u + 0x7FFFu + ((v.u >> 16) & 1u)) >> 16;
  return (unsigned short)r;
}
DI float fast_tanh(float x) {
  float e = __expf(2.0f * x);
  return 1.0f - 2.0f / (e + 1.0f);
}

// ---------------- kpack: W -> bf16 fragment-linear Wf (16x16x32 layout, R18-verbatim) ----
__global__ __launch_bounds__(256) void kpack(const float* __restrict__ bw,
                                             const float* __restrict__ sw,
                                             unsigned short* __restrict__ Wf) {
  int idx = blockIdx.x * 256 + threadIdx.x;   // o*384 + i
  int o = idx / IN_DIM;
  int i = idx - o * IN_DIM;
  const float* sp = sw + (size_t)idx * 19;
  const uint32_t gq  = (uint32_t)(o >> 4);
  const uint32_t l16o = (uint32_t)(o & 15);
#pragma unroll
  for (int c = 0; c < 20; ++c) {
    int k = i * 20 + c;
    uint32_t q  = (uint32_t)k >> 5;
    uint32_t kr = (uint32_t)k & 31u;
    uint32_t lane = l16o + ((kr >> 3) << 4);
    uint32_t off = (q * 32u + gq) * 512u + lane * 8u + (kr & 7u);
    float v = (c == 0) ? bw[idx] : sp[c - 1];
    Wf[off] = f2bf(v);
  }
}

// ---------------- kpackL: lw [64][512] fp32 -> bf16 fragment-linear lwf ----------------
// Element (ocol,k): g = ocol>>4 (4 frags), q = k>>5 (16 planes);
// lane = (ocol&15) + ((k>>3)&3)*16; off = (q*4 + g)*512 + lane*8 + (k&7).
__global__ __launch_bounds__(256) void kpackL(const float* __restrict__ lw,
                                              unsigned short* __restrict__ lwf) {
  int idx = blockIdx.x * 256 + threadIdx.x;   // [0, 32768)
  int ocol = idx >> 9;
  int k    = idx & 511;
  uint32_t g = (uint32_t)(ocol >> 4);
  uint32_t q = (uint32_t)k >> 5;
  uint32_t lane = (uint32_t)(ocol & 15) + (((uint32_t)(k >> 3) & 3u) << 4);
  lwf[(q * 4u + g) * 512u + lane * 8u + ((uint32_t)k & 7u)] = f2bf(lw[idx]);
}

// ---------------- fused KAN GEMM + final: out = tanh(A(x)@W^T) @ lw^T + lb ----------------
__global__ __launch_bounds__(512, 4) void kgemm1(const float* __restrict__ z,
                                                 const float* __restrict__ ms,
                                                 const float* __restrict__ md,
                                                 const unsigned short* __restrict__ Wf,
                                                 const unsigned short* __restrict__ lwf,
                                                 const float* __restrict__ lb,
                                                 float* __restrict__ out) {
  extern __shared__ char ldsbuf[];            // loop: [A0 @0][A1 @20480]; epilogue: h-tile 64KB

  const int tid  = threadIdx.x;
  const int lane = tid & 63;
  const int wc   = tid >> 6;                  // 0..7 : N strip (64 cols); all waves share rows
  const int l16  = lane & 15;
  const int lhi  = lane >> 4;

  // XCD-aware bijective swizzle: grid 512 = 8 XCD * 64 (pure M split; every block scans W)
  int wg = blockIdx.x;
  int id = (wg & 7) * 64 + (wg >> 3);
  const int row0 = id * BM;

  // B global fragment base: g = wc*4 + ni in [0,32); q = s*5 + ks (frag stride 16384 elems)
  const unsigned short* bpt = Wf + (size_t)(wc * 4) * 512 + (size_t)lane * 8;

  // A-gen: exactly ONE task per thread (64 rows x 8 isl = 512)
  const int isl = tid & 7;
  const int arow = tid >> 3;                  // 0..63
  const uint32_t fw = ((uint32_t)arow & 7u) << 4;
  const uint32_t abase = (uint32_t)arow * A_STRIDE_B + (uint32_t)isl * 40u;

  // A fragment read base (XOR applied to full address; R18-verbatim)
  const uint32_t fA = (uint32_t)(l16 & 7) << 4;      // row&7 = l16&7
  const uint32_t rA = (uint32_t)l16 * A_STRIDE_B + (uint32_t)lhi * 16u;

  f32x4 acc[4][4] = {};

  // ---- prologue: stage A(0) into parity 0; prefetch x(1)
  float xv0;
  {
    float x = z[(size_t)(row0 + arow) * 128 + isl];   // s=0 -> i=isl<128 -> z
    float xt = fast_tanh(x);
    float tt = (xt + 1.0f) * 8.0f;
    int   m  = (int)tt; m = m > 16 ? 16 : m;
    float u  = tt - (float)m;
    float omu = 1.0f - u;
    float u2 = u * u, u3 = u2 * u;
    float w0 = omu * omu * omu * (1.0f / 6.0f);
    float w1 = (3.0f * u3 - 6.0f * u2 + 4.0f) * (1.0f / 6.0f);
    float w2 = (-3.0f * u3 + 3.0f * u2 + 3.0f * u + 1.0f) * (1.0f / 6.0f);
    float w3 = u3 * (1.0f / 6.0f);
    float sil = xt / (1.0f + __expf(-xt));
#pragma unroll
    for (int zz = 0; zz < 5; ++zz)
      *(uint64_t*)(ldsbuf + ((abase + zz * 8) ^ fw)) = 0ull;
    *(short*)(ldsbuf + (abase ^ fw)) = (short)f2bf(sil);
    *(short*)(ldsbuf + ((abase + 2u * (m + 1)) ^ fw)) = (short)f2bf(w0);
    *(short*)(ldsbuf + ((abase + 2u * (m + 2)) ^ fw)) = (short)f2bf(w1);
    *(short*)(ldsbuf + ((abase + 2u * (m + 3)) ^ fw)) = (short)f2bf(w2);
    if (m < 16)
      *(short*)(ldsbuf + ((abase + 2u * (m + 4)) ^ fw)) = (short)f2bf(w3);
    xv0 = z[(size_t)(row0 + arow) * 128 + 8 + isl];   // x(1)
  }
  __syncthreads();

  for (int s = 0; s < NSTEP; ++s) {
    const uint32_t pc = (uint32_t)(s & 1);
    const uint32_t pn = pc ^ 1u;
    char* An = ldsbuf + pn * (uint32_t)A_BYTES;
    const char* Ac = ldsbuf + pc * (uint32_t)A_BYTES;

    // ---- stage A(s+1) into An using xv0 = x(s+1) -- UNCONDITIONAL (branchless; step-48
    // tile is unread, reads memory-safe)
    {
      float xt = fast_tanh(xv0);
      float tt = (xt + 1.0f) * 8.0f;
      int   m  = (int)tt; m = m > 16 ? 16 : m;
      float u  = tt - (float)m;
      float omu = 1.0f - u;
      float u2 = u * u, u3 = u2 * u;
      float w0 = omu * omu * omu * (1.0f / 6.0f);
      float w1 = (3.0f * u3 - 6.0f * u2 + 4.0f) * (1.0f / 6.0f);
      float w2 = (-3.0f * u3 + 3.0f * u2 + 3.0f * u + 1.0f) * (1.0f / 6.0f);
      float w3 = u3 * (1.0f / 6.0f);
      float sil = xt / (1.0f + __expf(-xt));
#pragma unroll
      for (int zz = 0; zz < 5; ++zz)
        *(uint64_t*)(An + ((abase + zz * 8) ^ fw)) = 0ull;
      *(short*)(An + (abase ^ fw)) = (short)f2bf(sil);
      *(short*)(An + ((abase + 2u * (m + 1)) ^ fw)) = (short)f2bf(w0);
      *(short*)(An + ((abase + 2u * (m + 2)) ^ fw)) = (short)f2bf(w1);
      *(short*)(An + ((abase + 2u * (m + 3)) ^ fw)) = (short)f2bf(w2);
      if (m < 16)
        *(short*)(An + ((abase + 2u * (m + 4)) ^ fw)) = (short)f2bf(w3);
    }
    // ---- prefetch x(s+2), branchless: index wraps mod IN_DIM (wrapped value unused)
    float xn0;
    {
      int i = (s + 2) * 8 + isl;
      i = (i >= IN_DIM) ? (i - IN_DIM) : i;
      const float* src = (i < 128) ? z : (i < 256 ? ms : md);
      xn0 = src[(size_t)(row0 + arow) * 128 + (i & 127)];
    }

    // ---- compute(s): A frags from LDS (parity pc), B frags as coalesced 1KB global loads
    const size_t qoff = (size_t)s * 5u * 16384u;   // q = s*5 + ks
#pragma unroll
    for (int ks = 0; ks < 5; ++ks) {
      bf16x8 af[4], bfr[4];
#pragma unroll
      for (int ni = 0; ni < 4; ++ni)
        bfr[ni] = *(const bf16x8*)(bpt + qoff + (size_t)ks * 16384u + (size_t)ni * 512u);
#pragma unroll
      for (int mi = 0; mi < 4; ++mi)
        af[mi] = *(const bf16x8*)(Ac + ((rA + (uint32_t)(mi * 16) * A_STRIDE_B + ks * 64u) ^ fA));
#pragma unroll
      for (int mi = 0; mi < 4; ++mi)
#pragma unroll
        for (int ni = 0; ni < 4; ++ni)
          acc[mi][ni] = __builtin_amdgcn_mfma_f32_16x16x32_bf16(af[mi], bfr[ni], acc[mi][ni], 0, 0, 0);
    }

    __syncthreads();   // one barrier: A(s+1) writes visible; Ac safe to overwrite next step
    xv0 = xn0;
  }

  // ==== fused final: out = tanh(h) @ lw^T + lb, entirely in-block ====
  // 1. write tanh(acc) -> bf16 h-tile [64][512] in LDS, row stride 1024B, XOR swizzle
#pragma unroll
  for (int mi = 0; mi < 4; ++mi)
#pragma unroll
    for (int ni = 0; ni < 4; ++ni)
#pragma unroll
      for (int rg = 0; rg < 4; ++rg) {
        int hrow = mi * 16 + lhi * 4 + rg;
        int hcol = wc * 64 + ni * 16 + l16;
        uint32_t ha = (uint32_t)hrow * 1024u + (uint32_t)hcol * 2u;
        *(short*)(ldsbuf + (ha ^ (((uint32_t)hrow & 7u) << 4))) =
            (short)f2bf(fast_tanh(acc[mi][ni][rg]));
      }
  __syncthreads();

  // 2. each wave: rows strip (wc>>1)*16, ocols (wc&1)*32; B-frags = coalesced lwf loads
  {
    const int rs  = (wc >> 1) * 16;
    const int oc0 = (wc & 1) * 32;
    const int g0  = (wc & 1) * 2;              // lwf fragment column group
    const uint32_t rh = (uint32_t)(rs + l16) * 1024u + (uint32_t)lhi * 16u;
    const uint32_t fH = (uint32_t)(l16 & 7) << 4;   // (rs+l16)&7 = l16&7 (rs mult of 16)
    const unsigned short* lpt = lwf + (size_t)g0 * 512 + (size_t)lane * 8;
    f32x4 acc2[2] = {};
#pragma unroll
    for (int ks = 0; ks < 16; ++ks) {
      bf16x8 ah = *(const bf16x8*)(ldsbuf + ((rh + (uint32_t)ks * 64u) ^ fH));
#pragma unroll
      for (int ni = 0; ni < 2; ++ni) {
        bf16x8 bh = *(const bf16x8*)(lpt + (size_t)(ks * 4 + ni) * 512u);
        acc2[ni] = __builtin_amdgcn_mfma_f32_16x16x32_bf16(ah, bh, acc2[ni], 0, 0, 0);
      }
    }
#pragma unroll
    for (int ni = 0; ni < 2; ++ni) {
      int ocol = oc0 + ni * 16 + l16;
      float bias = lb[ocol];
#pragma unroll
      for (int rg = 0; rg < 4; ++rg) {
        int grow = row0 + rs + lhi * 4 + rg;
        out[(size_t)grow * 64 + ocol] = acc2[ni][rg] + bias;
      }
    }
  }
}

extern "C" void kernel_launch(void* const* d_in, const int* in_sizes, int n_in,
                              void* d_out, int out_size, void* d_ws, size_t ws_size,
                              hipStream_t stream) {
  const float* z  = (const float*)d_in[0];
  const float* ms = (const float*)d_in[1];
  const float* md = (const float*)d_in[2];
  const float* bw = (const float*)d_in[3];
  const float* sw = (const float*)d_in[4];
  const float* lw = (const float*)d_in[5];
  const float* lb = (const float*)d_in[6];
  float* out = (float*)d_out;

  unsigned short* Wf  = (unsigned short*)d_ws;                        // 7.5 MiB fragment-linear W
  unsigned short* lwf = (unsigned short*)((char*)d_ws + (8u << 20));  // 64 KiB fragment-linear lw

  (void)hipFuncSetAttribute((const void*)kgemm1,
                            hipFuncAttributeMaxDynamicSharedMemorySize, LDS_BYTES);

  kpack<<<(HID * IN_DIM) / 256, 256, 0, stream>>>(bw, sw, Wf);
  kpackL<<<(64 * 512) / 256, 256, 0, stream>>>(lw, lwf);
  kgemm1<<<512, 512, LDS_BYTES, stream>>>(z, ms, md, Wf, lwf, lb, out);
}